// Round 7
// baseline (756.870 us; speedup 1.0000x reference)
//
#include <hip/hip_runtime.h>
#include <cstdint>

#define BB 64
#define SS 512
#define TT 32
#define DD 1024
#define MM (BB*SS)     // 32768 rows
#define NC 32          // CRF chunks per batch
#define CHK 16         // steps per chunk

typedef __attribute__((address_space(3))) uint32_t lds_u32;
typedef __attribute__((address_space(1))) const uint32_t g_u32;

__device__ __forceinline__ void gload16(const float* g, float* l) {
    __builtin_amdgcn_global_load_lds((g_u32*)g, (lds_u32*)l, 16, 0, 0);
}
__device__ __forceinline__ float rl(float v, int l) {
    return __uint_as_float(__builtin_amdgcn_readlane(__float_as_uint(v), l));
}
// reduce within each 32-lane half: xor offsets <32 never cross the half
#define HALF_MAX(M) do { \
    M = fmaxf(M, __shfl_xor(M, 1));  \
    M = fmaxf(M, __shfl_xor(M, 2));  \
    M = fmaxf(M, __shfl_xor(M, 4));  \
    M = fmaxf(M, __shfl_xor(M, 8));  \
    M = fmaxf(M, __shfl_xor(M, 16)); } while(0)
#define HALF_SUM(M) do { \
    M += __shfl_xor(M, 1);  \
    M += __shfl_xor(M, 2);  \
    M += __shfl_xor(M, 4);  \
    M += __shfl_xor(M, 8);  \
    M += __shfl_xor(M, 16); } while(0)

// ---------------------------------------------------------------------------
// Kernel 1: emissions GEMM  emis[32768][32] = A[32768][1024] @ W[1024][32] + b
// grid 512, block 256 (4 waves), 64 rows/block; wave w owns K-quarter.
// Thread = one row (row = lane), all 32 cols in acc[32].
// A staged per-wave via global_load_lds w16, double-buffered, XOR-swizzled
// source -> conflict-free ds_read_b128.  W rows: readfirstlane-uniform
// addresses -> s_load (SMEM pipe, scalar-cache-hot, no VALU/VMEM cost).
// Epilogue: 4-way K-partial reduction through LDS, coalesced C write.
// ---------------------------------------------------------------------------
__global__ __launch_bounds__(256, 2) void gemm_emit(
    const float* __restrict__ A, const float* __restrict__ Wg,
    const float* __restrict__ bias, float* __restrict__ C)
{
    __shared__ float smem[16384];     // 4 waves x dbuf x 2048 floats = 64 KB

    const int tid = threadIdx.x;
    const int w = tid >> 6, lane = tid & 63;
    const int wu = __builtin_amdgcn_readfirstlane(w);   // uniform wave id (SGPR)
    const int row0 = blockIdx.x * 64;
    float* bufs = &smem[w * 4096];

    float acc[32];
#pragma unroll
    for (int q = 0; q < 32; ++q) acc[q] = 0.f;

    const int srck4 = (lane & 7) ^ (lane >> 3);   // inverse-swizzled source slot

    auto issue = [&](int ch) {
        const int kb = w * 256 + ch * 32;
        float* dst = bufs + (ch & 1) * 2048;
#pragma unroll
        for (int i = 0; i < 8; ++i)
            gload16(&A[(size_t)(row0 + i * 8 + (lane >> 3)) * DD + kb + srck4 * 4],
                    dst + i * 256);
    };

    issue(0);
#pragma unroll 1
    for (int ch = 0; ch < 8; ++ch) {
        if (ch < 7) {
            // prior iteration's ds_reads fully drained -> safe to overwrite buf
            asm volatile("s_waitcnt lgkmcnt(0)" ::: "memory");
            issue(ch + 1);
            asm volatile("s_waitcnt vmcnt(8)" ::: "memory");
        } else {
            asm volatile("s_waitcnt vmcnt(0)" ::: "memory");
        }
        const float* bc = bufs + (ch & 1) * 2048;
        const int kbu = wu * 256 + ch * 32;          // uniform -> s_load path
        float4 av[8];
#pragma unroll
        for (int k4 = 0; k4 < 8; ++k4)
            av[k4] = *(const float4*)&bc[lane * 32 + ((k4 ^ (lane & 7)) << 2)];
#pragma unroll
        for (int k4 = 0; k4 < 8; ++k4) {
            float am[4] = {av[k4].x, av[k4].y, av[k4].z, av[k4].w};
#pragma unroll
            for (int kk = 0; kk < 4; ++kk) {
                const float* wrow = &Wg[(size_t)(kbu + k4 * 4 + kk) * TT];
#pragma unroll
                for (int c8 = 0; c8 < 8; ++c8) {
                    float4 wv = *(const float4*)&wrow[c8 * 4];  // s_load_dwordx4
                    acc[c8*4+0] = fmaf(am[kk], wv.x, acc[c8*4+0]);
                    acc[c8*4+1] = fmaf(am[kk], wv.y, acc[c8*4+1]);
                    acc[c8*4+2] = fmaf(am[kk], wv.z, acc[c8*4+2]);
                    acc[c8*4+3] = fmaf(am[kk], wv.w, acc[c8*4+3]);
                }
            }
        }
    }

    // cross-wave K reduction (stride 36 breaks bank degeneracy)
    __syncthreads();
    float* red = smem;                 // 256*36 floats = 36 KB (reuse bufs)
#pragma unroll
    for (int q4 = 0; q4 < 8; ++q4)
        *(float4*)&red[tid * 36 + q4 * 4] =
            make_float4(acc[q4*4], acc[q4*4+1], acc[q4*4+2], acc[q4*4+3]);
    __syncthreads();

    const int r = tid >> 2, cg = tid & 3;
    float4 o0 = make_float4(0,0,0,0), o1 = o0;
#pragma unroll
    for (int ww = 0; ww < 4; ++ww) {
        const float* rb = &red[(ww * 64 + r) * 36 + cg * 8];
        float4 a4 = *(const float4*)&rb[0];
        float4 b4 = *(const float4*)&rb[4];
        o0.x += a4.x; o0.y += a4.y; o0.z += a4.z; o0.w += a4.w;
        o1.x += b4.x; o1.y += b4.y; o1.z += b4.z; o1.w += b4.w;
    }
    float4 bb0 = *(const float4*)&bias[cg * 8];
    float4 bb1 = *(const float4*)&bias[cg * 8 + 4];
    o0.x += bb0.x; o0.y += bb0.y; o0.z += bb0.z; o0.w += bb0.w;
    o1.x += bb1.x; o1.y += bb1.y; o1.z += bb1.z; o1.w += bb1.w;
    *(float4*)&C[(size_t)(row0 + r) * TT + cg * 8]     = o0;
    *(float4*)&C[(size_t)(row0 + r) * TT + cg * 8 + 4] = o1;
}

// ---------------------------------------------------------------------------
// Kernel 2: CRF phase 1 — chunk product matrices (parallel scan, phase A).
// grid 512 (8 blocks/batch), block 128 (4 half-waves); half-wave = one
// (batch, chunk): lane r holds row r of P (32 floats).
// Step: P <- P * (ET * diag(x_t)) — lane-local FMA; ET broadcast from LDS.
// Inner product q8-outer (4 live accumulators) to cap register pressure
// without scheduling fences.  Renorm by global max every 4 steps.
// ---------------------------------------------------------------------------
__global__ __launch_bounds__(128) void crf_phase1(
    const float* __restrict__ emis, const int* __restrict__ tags,
    const float* __restrict__ trans, float* __restrict__ P, float* __restrict__ Ls)
{
    __shared__ float ex[4 * CHK * 32];   // 8 KB: 4 local chunks
    __shared__ float ET[32 * 32];        // 4 KB
    __shared__ int s_len;

    const int tid = threadIdx.x;
    const int b  = blockIdx.x >> 3;           // 8 blocks per batch
    const int c0 = (blockIdx.x & 7) * 4;      // first chunk of this block
    const int pl = tid >> 5;                  // local half-wave 0..3
    const int r  = tid & 31;                  // row of P
    const int c  = c0 + pl;                   // chunk id 0..31

    if (tid == 0) s_len = SS;
    __syncthreads();
    for (int t = tid; t < SS; t += 128)
        if (tags[b * SS + t] < 0) atomicMin(&s_len, t);
#pragma unroll
    for (int u = 0; u < 8; ++u) {
        int e = u * 128 + tid;
        ET[e] = __expf(trans[e]);
    }
    // stage exp(emissions) for the block's 4 chunks
#pragma unroll 1
    for (int u = 0; u < 16; ++u) {
        int e = u * 128 + tid;                // 0..2047
        int epl = e >> 9, s = (e >> 5) & 15, jj = e & 31;
        int t = (c0 + epl) * CHK + 1 + s;
        ex[e] = (t < SS) ? __expf(emis[((size_t)b * SS + t) * TT + jj]) : 1.0f;
    }
    __syncthreads();
    const int len = s_len;
    const float* exh = &ex[pl * (CHK * 32)];

    float p[32];
#pragma unroll
    for (int q = 0; q < 32; ++q) p[q] = (q == r) ? 1.f : 0.f;
    float cs = 0.f;

#pragma unroll 1
    for (int g = 0; g < 4; ++g) {
#pragma unroll 1
        for (int u = 0; u < 4; ++u) {
            const int s = g * 4 + u;
            if (c * CHK + 1 + s < len) {
                float pn[32];
#pragma unroll
                for (int q8 = 0; q8 < 8; ++q8) {
                    float a0 = 0.f, a1 = 0.f, a2 = 0.f, a3 = 0.f;
#pragma unroll
                    for (int i = 0; i < 32; ++i) {
                        float4 et = *(const float4*)&ET[i * 32 + q8 * 4];
                        a0 = fmaf(p[i], et.x, a0);
                        a1 = fmaf(p[i], et.y, a1);
                        a2 = fmaf(p[i], et.z, a2);
                        a3 = fmaf(p[i], et.w, a3);
                    }
                    float4 xv = *(const float4*)&exh[s * 32 + q8 * 4];
                    pn[q8*4+0] = a0 * xv.x;
                    pn[q8*4+1] = a1 * xv.y;
                    pn[q8*4+2] = a2 * xv.z;
                    pn[q8*4+3] = a3 * xv.w;
                }
#pragma unroll
                for (int q = 0; q < 32; ++q) p[q] = pn[q];
            }
        }
        // renorm: lane-local max, then across the 32 rows
        float M = p[0];
#pragma unroll
        for (int q = 1; q < 32; ++q) M = fmaxf(M, p[q]);
        HALF_MAX(M);
        float rM = __builtin_amdgcn_rcpf(M);
#pragma unroll
        for (int q = 0; q < 32; ++q) p[q] *= rM;
        cs += __logf(M);
    }

    const int pair = b * NC + c;
#pragma unroll
    for (int q4 = 0; q4 < 8; ++q4)
        *(float4*)&P[((size_t)pair * 32 + r) * 32 + q4 * 4] =
            make_float4(p[q4*4], p[q4*4+1], p[q4*4+2], p[q4*4+3]);
    if (r == 0) Ls[pair] = cs;
}

// ---------------------------------------------------------------------------
// Kernel 3: CRF phase 2 — score + sequential chunk application + logZ.
// One wave per batch; P read directly from global (L2-hot, coalesced).
// ---------------------------------------------------------------------------
__global__ __launch_bounds__(64) void crf_phase2(
    const float* __restrict__ emis, const int* __restrict__ tags,
    const float* __restrict__ start_t, const float* __restrict__ end_t,
    const float* __restrict__ trans, const float* __restrict__ P,
    const float* __restrict__ Ls, float* __restrict__ out)
{
    const int b = blockIdx.x;
    const int lane = threadIdx.x, jj = lane & 31;
    const int* tb = tags + b * SS;

    // length (mask is a prefix)
    int fneg = SS;
    for (int t = lane; t < SS; t += 64)
        if (tb[t] < 0) fneg = min(fneg, t);
#pragma unroll
    for (int off = 32; off; off >>= 1)
        fneg = min(fneg, __shfl_xor(fneg, off));
    const int len = fneg;

    // numerator score (emis already includes bias)
    float sc = 0.f;
    for (int t = lane; t < len; t += 64) {
        int tg = tb[t];
        float e = emis[((size_t)b * SS + t) * TT + tg];
        if (t == 0) sc += start_t[tg] + e;
        else        sc += trans[tb[t - 1] * TT + tg] + e;
    }
#pragma unroll
    for (int off = 32; off; off >>= 1) sc += __shfl_xor(sc, off);
    const float score = sc + end_t[tb[len - 1]];

    // alpha0 in exp space
    float v0 = start_t[jj] + emis[(size_t)b * SS * TT + jj];
    float m = v0; HALF_MAX(m);
    float A = __expf(v0 - m);
    float logoff = m;

#pragma unroll 1
    for (int cc = 0; cc < NC; ++cc) {
        const float* Pc = &P[((size_t)b * NC + cc) * 1024];
        float s0 = 0.f, s1 = 0.f, s2 = 0.f, s3 = 0.f;
#pragma unroll
        for (int i = 0; i < 32; i += 4) {
            s0 = fmaf(rl(A, i+0), Pc[(i+0)*32 + jj], s0);
            s1 = fmaf(rl(A, i+1), Pc[(i+1)*32 + jj], s1);
            s2 = fmaf(rl(A, i+2), Pc[(i+2)*32 + jj], s2);
            s3 = fmaf(rl(A, i+3), Pc[(i+3)*32 + jj], s3);
        }
        float S = (s0 + s1) + (s2 + s3);
        float M = S; HALF_MAX(M);
        A = S * __builtin_amdgcn_rcpf(M);
        logoff += __logf(M) + Ls[b * NC + cc];
    }

    float z = A * __expf(end_t[jj]);
    HALF_SUM(z);
    const float log_z = logoff + __logf(z);

    if (lane == 0)
        atomicAdd(out, (log_z - score) * (1.0f / BB));
}

// ---------------------------------------------------------------------------
extern "C" void kernel_launch(void* const* d_in, const int* in_sizes, int n_in,
                              void* d_out, int out_size, void* d_ws, size_t ws_size,
                              hipStream_t stream) {
    const float* feat = (const float*)d_in[0];
    const int*   tags = (const int*)  d_in[1];
    const float* W    = (const float*)d_in[2];
    const float* bias = (const float*)d_in[3];
    const float* st   = (const float*)d_in[4];
    const float* en   = (const float*)d_in[5];
    const float* tr   = (const float*)d_in[6];
    float* out  = (float*)d_out;
    float* emis = (float*)d_ws;                        // 4 MB
    float* P    = emis + (size_t)MM * TT;              // 8 MB (64*32*32*32)
    float* Ls   = P + (size_t)BB * NC * 32 * 32;       // 8 KB

    (void)hipMemsetAsync(out, 0, sizeof(float), stream);
    gemm_emit<<<MM / 64, 256, 0, stream>>>(feat, W, bias, emis);
    crf_phase1<<<BB * 8, 128, 0, stream>>>(emis, tags, tr, P, Ls);
    crf_phase2<<<BB, 64, 0, stream>>>(emis, tags, st, en, tr, P, Ls, out);
}